// Round 4
// baseline (242.379 us; speedup 1.0000x reference)
//
#include <hip/hip_runtime.h>

// Performer (FAVOR+) attention, MI355X bf16-MFMA implementation.
// Round 4: (a) deeper staging schedule — stage {q0:A0(T+1), q1:A1(T+1),
// q2:B0(T+2), q3:B1(T+2)}, vmcnt(4) at q3 (youngest target issued 2+ phases
// earlier; R3's vmcnt(2) waited on a 1-phase-old load -> per-K-tile stall).
// (b) swapped-operand MFMA (b,a) -> fragment holds 4 consecutive C-columns
// per lane -> packed 8B/16B epilogue stores (32/thread instead of 128).

typedef __attribute__((ext_vector_type(8))) short s8v;   // 8 x bf16 (4 VGPR)
typedef __attribute__((ext_vector_type(4))) short s4v;   // 4 x bf16
typedef __attribute__((ext_vector_type(4))) float f4v;   // MFMA acc
typedef __attribute__((ext_vector_type(4))) int   i4v;   // 16B chunk

#define MFMA16(a, b, c) __builtin_amdgcn_mfma_f32_16x16x32_bf16((a), (b), (c), 0, 0, 0)

__device__ __forceinline__ unsigned short f2bf(float f) {
  unsigned int u = __builtin_bit_cast(unsigned int, f);
  unsigned int r = (u + 0x7FFFu + ((u >> 16) & 1u)) >> 16;  // RNE
  return (unsigned short)r;
}

__device__ __forceinline__ int swz(int p) {          // involution, bits 7..9 -> 4..6
  return p ^ (((p >> 7) & 7) << 4);
}

__device__ __forceinline__ void gl_lds16(const void* g, void* l) {
  __builtin_amdgcn_global_load_lds(
      (const __attribute__((address_space(1))) void*)g,
      (__attribute__((address_space(3))) void*)l, 16, 0, 0);
}

// ---------------------------------------------------------------- prep
__global__ __launch_bounds__(256) void cvt_bf16(const float* __restrict__ in,
                                                unsigned short* __restrict__ out,
                                                int n4) {
  int i = blockIdx.x * 256 + threadIdx.x;
  if (i >= n4) return;
  f4v v = ((const f4v*)in)[i];
  s4v o;
#pragma unroll
  for (int j = 0; j < 4; ++j) o[j] = (short)f2bf(v[j]);
  ((s4v*)out)[i] = o;
}

// out[z][c][r] = bf16(in[z][r][c]); R,C multiples of 32. block (32,8)
__global__ __launch_bounds__(256) void transpose_cvt(const float* __restrict__ in,
                                                     unsigned short* __restrict__ out,
                                                     int R, int C) {
  __shared__ float tile[32][33];
  const int tx = threadIdx.x, ty = threadIdx.y;
  const int z = blockIdx.z;
  const float* inz = in + (size_t)z * R * C;
  unsigned short* outz = out + (size_t)z * R * C;
  const int c0 = blockIdx.x * 32, r0 = blockIdx.y * 32;
#pragma unroll
  for (int j = 0; j < 4; ++j)
    tile[ty + j * 8][tx] = inz[(size_t)(r0 + ty + j * 8) * C + c0 + tx];
  __syncthreads();
#pragma unroll
  for (int j = 0; j < 4; ++j)
    outz[(size_t)(c0 + ty + j * 8) * R + r0 + tx] = f2bf(tile[tx][ty + j * 8]);
}

// ---------------------------------------------------------------- GEMM 256x256
// C[M,N] = A[M,K] @ Bt[N,K]^T.  8-phase schedule, BK=64, 512 threads (8 waves,
// 2Mx4N), 128 KiB LDS = 2 dbuf x {A,B} x 2 halves x [128 rows][64 cols] bf16.
// LDS swizzle p ^= ((p>>7)&7)<<4 as inverse-swizzled global source + swizzled
// ds_read (rule 21). Phases: q0=(0,0), q1=(0,1), q2=(1,1), q3=(1,0).
// Staging: q0:A0(T+1) q1:A1(T+1) q2:B0(T+2) q3:B1(T+2); vmcnt(4) at q3
// (keeps B(T+2) in flight, guarantees tile T+1 fully landed). Region safety:
// A regions last read at q2 (restaged next tile's q0/q1 after bar2), B regions
// last read at q1 (restaged same tile's q2/q3) — all barrier-separated.
template <int MODE>
__global__ __launch_bounds__(512, 2) void gemm256(const unsigned short* __restrict__ A,
                                                  const unsigned short* __restrict__ Bt,
                                                  void* __restrict__ Cout,
                                                  const float* __restrict__ bias,
                                                  int Nn, int K, int NTN, int CPX) {
  __shared__ __align__(128) unsigned short smem[65536];  // 128 KiB
  const int t = threadIdx.x, w = t >> 6, lane = t & 63;
  const int wm = w >> 2, wn = w & 3;
  const int fr = lane & 15, c16 = (lane >> 4) * 16;
  const int nkt = K >> 6;

  // T1: XCD-bijective block swizzle (grid % 8 == 0)
  const int bid = blockIdx.x;
  const int wg = (bid & 7) * CPX + (bid >> 3);
  const int tm = wg / NTN, tn = wg % NTN;

  const unsigned short* gA = A + (size_t)tm * 256 * K;
  const unsigned short* gB = Bt + (size_t)tn * 256 * K;

  // per-thread pre-swizzled global source offsets for the 2 staging loads
  const int s0 = swz(t * 16);
  const int s1 = swz(8192 + t * 16);
  const int goff0 = (s0 >> 7) * K + ((s0 & 127) >> 1);
  const int goff1 = ((s1 - 8192) >> 7) * K + ((s1 & 127) >> 1) + 64 * K;
  const int woff = w * 1024;  // wave-uniform LDS byte offset

  auto stage = [&](int T2, int part) {
    if (T2 >= nkt) return;
    char* reg = (char*)smem + (((T2 & 1) * 4 + part) << 14);
    const unsigned short* gp =
        (part < 2 ? gA : gB) + (size_t)((part & 1) * 128) * K + T2 * 64;
    gl_lds16(gp + goff0, reg + woff);
    gl_lds16(gp + goff1, reg + 8192 + woff);
  };

  f4v acc[8][4] = {};

  // prologue: tile0 all 4 halves + tile1 B halves; drain tile0, keep B(1) flying
  stage(0, 0); stage(0, 1); stage(0, 2); stage(0, 3);
  stage(1, 2); stage(1, 3);
  if (nkt > 1) { asm volatile("s_waitcnt vmcnt(4)" ::: "memory"); }
  else         { asm volatile("s_waitcnt vmcnt(0)" ::: "memory"); }
  __builtin_amdgcn_s_barrier();
  __builtin_amdgcn_sched_barrier(0);

  auto rdA = [&](int mh, s8v (&a)[4][2], const char* Ar) {
#pragma unroll
    for (int i = 0; i < 4; ++i)
#pragma unroll
      for (int ks = 0; ks < 2; ++ks) {
        int p = swz((mh * 64 + i * 16 + fr) * 128 + ks * 64 + c16);
        a[i][ks] = *(const s8v*)(Ar + p);
      }
  };
  auto rdB = [&](int nh, s8v (&b)[2][2], const char* Br, int brow) {
#pragma unroll
    for (int j = 0; j < 2; ++j)
#pragma unroll
      for (int ks = 0; ks < 2; ++ks) {
        int p = swz((brow + nh * 32 + j * 16 + fr) * 128 + ks * 64 + c16);
        b[j][ks] = *(const s8v*)(Br + p);
      }
  };
  // swapped operands: D-row <-> b (C-col), D-col <-> a (C-row).
  // acc[m][n][g] = C[rowbase + m*16 + fr][colbase + n*16 + (lane>>4)*4 + g]
  auto mmac = [&](int mh, int nh, const s8v (&a)[4][2], const s8v (&b)[2][2]) {
    __builtin_amdgcn_s_setprio(1);
#pragma unroll
    for (int i = 0; i < 4; ++i)
#pragma unroll
      for (int j = 0; j < 2; ++j) {
        acc[mh * 4 + i][nh * 2 + j] = MFMA16(b[j][0], a[i][0], acc[mh * 4 + i][nh * 2 + j]);
        acc[mh * 4 + i][nh * 2 + j] = MFMA16(b[j][1], a[i][1], acc[mh * 4 + i][nh * 2 + j]);
      }
    __builtin_amdgcn_s_setprio(0);
  };

  const int brow = (wn & 1) * 64;
  for (int T = 0; T < nkt; ++T) {
    const int d = T & 1;
    const char* Ar = (const char*)smem + ((d * 4 + wm) << 14);
    const char* Br = (const char*)smem + ((d * 4 + 2 + (wn >> 1)) << 14);
    s8v a[4][2], b0[2][2], b1[2][2];
    // q0: quadrant (0,0)
    rdA(0, a, Ar); rdB(0, b0, Br, brow); stage(T + 1, 0);
    __builtin_amdgcn_s_barrier();
    mmac(0, 0, a, b0);
    __builtin_amdgcn_s_barrier();
    __builtin_amdgcn_sched_barrier(0);
    // q1: quadrant (0,1) — reuse A
    rdB(1, b1, Br, brow); stage(T + 1, 1);
    __builtin_amdgcn_s_barrier();
    mmac(0, 1, a, b1);
    __builtin_amdgcn_s_barrier();
    __builtin_amdgcn_sched_barrier(0);
    // q2: quadrant (1,1) — reuse B1
    rdA(1, a, Ar); stage(T + 2, 2);
    __builtin_amdgcn_s_barrier();
    mmac(1, 1, a, b1);
    __builtin_amdgcn_s_barrier();
    __builtin_amdgcn_sched_barrier(0);
    // q3: quadrant (1,0) — no reads; counted wait: tile T+1 fully landed
    stage(T + 2, 3);
    if (T < nkt - 2)       { asm volatile("s_waitcnt vmcnt(4)" ::: "memory"); }
    else if (T == nkt - 2) { asm volatile("s_waitcnt vmcnt(0)" ::: "memory"); }
    __builtin_amdgcn_s_barrier();
    mmac(1, 0, a, b0);
    __builtin_amdgcn_s_barrier();
    __builtin_amdgcn_sched_barrier(0);
  }

  // epilogue: packed stores (4 consecutive C-cols per lane per fragment)
#pragma unroll
  for (int m = 0; m < 8; ++m)
#pragma unroll
    for (int n = 0; n < 4; ++n) {
      const int row = tm * 256 + wm * 128 + m * 16 + fr;
      const int col = tn * 256 + wn * 64 + n * 16 + (lane >> 4) * 4;
      if (MODE == 0) {
        unsigned short* C = (unsigned short*)Cout;
        s4v o;
#pragma unroll
        for (int g = 0; g < 4; ++g) o[g] = (short)f2bf(acc[m][n][g]);
        *(s4v*)&C[(size_t)row * Nn + col] = o;
      } else {
        float* C = (float*)Cout;
        const f4v bv = *(const f4v*)&bias[col];
        f4v o = acc[m][n] + bv;
        *(f4v*)&C[(size_t)row * Nn + col] = o;
      }
    }
}

// ---------------------------------------------------------------- phi_k + kv
// block = (och, h, b); processes 512 tokens in 4 chunks of 128.
// kvpart[bh][och][80][64]: rows 0..63 = kv^T (d,r), row 64 = k_sum, 65..79 = 0.
__global__ __launch_bounds__(256) void phik_kv(const unsigned short* __restrict__ qkv,
                                               const unsigned short* __restrict__ RFt,
                                               float* __restrict__ kvpart) {
  __shared__ unsigned short RFl[2 * 64 * 32];   // [p][r][32]
  __shared__ unsigned short Kl[2 * 128 * 32];   // [p][n][32]
  __shared__ unsigned short pht[64 * 136];      // [r][n] (+pad)
  __shared__ unsigned short vt[80 * 136];       // [d][n] (+ones row 64)
  const int t = threadIdx.x, w = t >> 6, lane = t & 63;
  const int och = blockIdx.x, h = blockIdx.y, b = blockIdx.z;
  const int fr = lane & 15, kg = (lane >> 4) * 8;

#pragma unroll
  for (int i = 0; i < 2; ++i) {  // RF[h] -> RFl
    int unit = i * 256 + w * 64 + lane;
    int p = unit >> 8, rem = unit & 255;
    int r = rem >> 2, cg = (rem & 3) * 8;
    gl_lds16(RFt + ((h * 64 + r) * 64 + p * 32 + cg), &RFl[(i * 256 + w * 64) * 8]);
  }
  for (int i = t; i < 136; i += 256) vt[64 * 136 + i] = 0x3F80;     // ones row
  for (int i = t; i < 15 * 136; i += 256) vt[65 * 136 + i] = 0;     // zero pad rows

  f4v kvacc[5] = {};

  for (int c = 0; c < 4; ++c) {
    const int n0c = och * 512 + c * 128;
    const size_t rowbase = (size_t)(b * 4096 + n0c);
#pragma unroll
    for (int i = 0; i < 4; ++i) {  // K slice -> Kl
      int unit = i * 256 + w * 64 + lane;
      int p = unit >> 9, rem = unit & 511;
      int n = rem >> 2, cg = (rem & 3) * 8;
      gl_lds16(qkv + (rowbase + n) * 3072 + 1024 + h * 64 + p * 32 + cg,
               &Kl[(i * 256 + w * 64) * 8]);
    }
    i4v vreg[4];
#pragma unroll
    for (int it = 0; it < 4; ++it) {  // V slice -> regs
      int slot = it * 256 + t;
      vreg[it] = *(const i4v*)&qkv[(rowbase + (slot >> 3)) * 3072 + 2048 + h * 64 +
                                   (slot & 7) * 8];
    }
    __syncthreads();
    // phi_k = relu(K @ RF)
    f4v pacc[2][4] = {};
#pragma unroll
    for (int p = 0; p < 2; ++p) {
      s8v ka[2], rb[4];
#pragma unroll
      for (int m = 0; m < 2; ++m)
        ka[m] = *(const s8v*)&Kl[p * 4096 + (w * 32 + m * 16 + fr) * 32 + kg];
#pragma unroll
      for (int rf = 0; rf < 4; ++rf)
        rb[rf] = *(const s8v*)&RFl[p * 2048 + (rf * 16 + fr) * 32 + kg];
#pragma unroll
      for (int m = 0; m < 2; ++m)
#pragma unroll
        for (int rf = 0; rf < 4; ++rf)
          pacc[m][rf] = MFMA16(ka[m], rb[rf], pacc[m][rf]);
    }
    // v -> vt (transposed)
#pragma unroll
    for (int it = 0; it < 4; ++it) {
      int slot = it * 256 + t;
      int vn = slot >> 3, vdh = (slot & 7) * 8;
      const unsigned short* vr = (const unsigned short*)&vreg[it];
#pragma unroll
      for (int j = 0; j < 8; ++j) vt[(vdh + j) * 136 + vn] = vr[j];
    }
    // phi -> pht (transposed, relu, bf16)
#pragma unroll
    for (int m = 0; m < 2; ++m)
#pragma unroll
      for (int rf = 0; rf < 4; ++rf) {
        int r = rf * 16 + fr;
        int nb = w * 32 + m * 16 + (lane >> 4) * 4;
        s4v pk;
#pragma unroll
        for (int g = 0; g < 4; ++g) pk[g] = (short)f2bf(fmaxf(pacc[m][rf][g], 0.0f));
        *(s4v*)&pht[r * 136 + nb] = pk;
      }
    __syncthreads();
    // kv_aug[d][r] += vt @ pht^T  (wave w owns r-cols w*16..+15)
#pragma unroll
    for (int kst = 0; kst < 4; ++kst) {
      s8v pb = *(const s8v*)&pht[(w * 16 + fr) * 136 + kst * 32 + kg];
#pragma unroll
      for (int f = 0; f < 5; ++f) {
        s8v va = *(const s8v*)&vt[(f * 16 + fr) * 136 + kst * 32 + kg];
        kvacc[f] = MFMA16(va, pb, kvacc[f]);
      }
    }
  }
  const int bh = b * 16 + h;
  float* outp = kvpart + ((size_t)bh * 8 + och) * (80 * 64);
#pragma unroll
  for (int f = 0; f < 5; ++f) {
    int row = f * 16 + (lane >> 4) * 4;
    int col = w * 16 + fr;
#pragma unroll
    for (int g = 0; g < 4; ++g) outp[(row + g) * 64 + col] = kvacc[f][g];
  }
}

__global__ __launch_bounds__(256) void kv_reduce(const float* __restrict__ kvpart,
                                                 unsigned short* __restrict__ kvt) {
  const int bh = blockIdx.x, t = threadIdx.x;
  for (int i = t; i < 80 * 64; i += 256) {
    float s = 0.f;
#pragma unroll
    for (int c = 0; c < 8; ++c) s += kvpart[((size_t)bh * 8 + c) * 5120 + i];
    kvt[(size_t)bh * 5120 + i] = f2bf(s);
  }
}

// ---------------------------------------------------------------- phi_q + out
// block = (ch, h, b); 128 tokens. attno[token][h*64+d] = (phi_q@kv)/(phi_q.k_sum+eps)
__global__ __launch_bounds__(256) void phiq_out(const unsigned short* __restrict__ qkv,
                                                const unsigned short* __restrict__ RFt,
                                                const unsigned short* __restrict__ kvt,
                                                unsigned short* __restrict__ attno) {
  __shared__ unsigned short RFl[2 * 64 * 32];  // [p][r][32]
  __shared__ unsigned short Ql[2 * 128 * 32];  // [p][n][32]
  __shared__ unsigned short phl[128 * 72];     // [n][r] (+pad)
  __shared__ unsigned short kvl[80 * 72];      // [d][r] (+pad), row 64 = k_sum
  const int t = threadIdx.x, w = t >> 6, lane = t & 63;
  const int ch = blockIdx.x, h = blockIdx.y, b = blockIdx.z;
  const int fr = lane & 15, kg = (lane >> 4) * 8;
  const int bh = b * 16 + h;
  const size_t rowbase = (size_t)(b * 4096 + ch * 128);

#pragma unroll
  for (int i = 0; i < 2; ++i) {
    int unit = i * 256 + w * 64 + lane;
    int p = unit >> 8, rem = unit & 255;
    int r = rem >> 2, cg = (rem & 3) * 8;
    gl_lds16(RFt + ((h * 64 + r) * 64 + p * 32 + cg), &RFl[(i * 256 + w * 64) * 8]);
  }
#pragma unroll
  for (int i = 0; i < 4; ++i) {
    int unit = i * 256 + w * 64 + lane;
    int p = unit >> 9, rem = unit & 511;
    int n = rem >> 2, cg = (rem & 3) * 8;
    gl_lds16(qkv + (rowbase + n) * 3072 + h * 64 + p * 32 + cg,
             &Ql[(i * 256 + w * 64) * 8]);
  }
  for (int i = t; i < 640; i += 256) {  // kvt -> kvl (pad 64->72)
    int row = i >> 3, cg = (i & 7) * 8;
    *(i4v*)&kvl[row * 72 + cg] = *(const i4v*)&kvt[(size_t)bh * 5120 + row * 64 + cg];
  }
  __syncthreads();
  f4v pacc[2][4] = {};
#pragma unroll
  for (int p = 0; p < 2; ++p) {
    s8v qa[2], rb[4];
#pragma unroll
    for (int m = 0; m < 2; ++m)
      qa[m] = *(const s8v*)&Ql[p * 4096 + (w * 32 + m * 16 + fr) * 32 + kg];
#pragma unroll
    for (int rf = 0; rf < 4; ++rf)
      rb[rf] = *(const s8v*)&RFl[p * 2048 + (rf * 16 + fr) * 32 + kg];
#pragma unroll
    for (int m = 0; m < 2; ++m)
#pragma unroll
      for (int rf = 0; rf < 4; ++rf)
        pacc[m][rf] = MFMA16(qa[m], rb[rf], pacc[m][rf]);
  }
#pragma unroll
  for (int m = 0; m < 2; ++m)
#pragma unroll
    for (int rf = 0; rf < 4; ++rf) {
      int r = rf * 16 + fr;
      int nb = w * 32 + m * 16 + (lane >> 4) * 4;
#pragma unroll
      for (int g = 0; g < 4; ++g)
        phl[(nb + g) * 72 + r] = f2bf(fmaxf(pacc[m][rf][g], 0.0f));
    }
  __syncthreads();
  f4v acc[2][5] = {};
#pragma unroll
  for (int kst = 0; kst < 2; ++kst) {
    s8v pa[2], kb[5];
#pragma unroll
    for (int m = 0; m < 2; ++m)
      pa[m] = *(const s8v*)&phl[(w * 32 + m * 16 + fr) * 72 + kst * 32 + kg];
#pragma unroll
    for (int f = 0; f < 5; ++f)
      kb[f] = *(const s8v*)&kvl[(f * 16 + fr) * 72 + kst * 32 + kg];
#pragma unroll
    for (int m = 0; m < 2; ++m)
#pragma unroll
      for (int f = 0; f < 5; ++f) acc[m][f] = MFMA16(pa[m], kb[f], acc[m][f]);
  }
#pragma unroll
  for (int m = 0; m < 2; ++m)
#pragma unroll
    for (int g = 0; g < 4; ++g) {
      float nrm = __shfl(acc[m][4][g], lane & 48) + 1e-6f;  // col 64 = phi_q.k_sum
      int n = w * 32 + m * 16 + (lane >> 4) * 4 + g;
      size_t orow = rowbase + n;
#pragma unroll
      for (int f = 0; f < 4; ++f)
        attno[orow * 1024 + h * 64 + f * 16 + fr] = f2bf(acc[m][f][g] / nrm);
    }
}

// ---------------------------------------------------------------- launch
extern "C" void kernel_launch(void* const* d_in, const int* in_sizes, int n_in,
                              void* d_out, int out_size, void* d_ws, size_t ws_size,
                              hipStream_t stream) {
  const float* x = (const float*)d_in[0];      // [4,4096,1024]
  const float* W_qkv = (const float*)d_in[1];  // [1024,3072]
  const float* RF = (const float*)d_in[2];     // [16,64,64]
  const float* W_out = (const float*)d_in[3];  // [1024,1024]
  const float* b_out = (const float*)d_in[4];  // [1024]
  float* out = (float*)d_out;                  // [4,4096,1024]

  char* ws = (char*)d_ws;
  size_t off = 0;
  auto alloc = [&](size_t bytes) -> void* {
    void* p = ws + off;
    off += (bytes + 255) & ~(size_t)255;
    return p;
  };
  unsigned short* xb = (unsigned short*)alloc(16384ull * 1024 * 2);
  unsigned short* wqkvt = (unsigned short*)alloc(3072ull * 1024 * 2);
  unsigned short* woutt = (unsigned short*)alloc(1024ull * 1024 * 2);
  unsigned short* rft = (unsigned short*)alloc(16ull * 64 * 64 * 2);
  unsigned short* qkv = (unsigned short*)alloc(16384ull * 3072 * 2);
  float* kvpart = (float*)alloc(64ull * 8 * 80 * 64 * 4);
  unsigned short* kvt = (unsigned short*)alloc(64ull * 80 * 64 * 2);
  unsigned short* attno = (unsigned short*)alloc(16384ull * 1024 * 2);

  cvt_bf16<<<16384, 256, 0, stream>>>(x, xb, 4194304);
  transpose_cvt<<<dim3(96, 32, 1), dim3(32, 8), 0, stream>>>(W_qkv, wqkvt, 1024, 3072);
  transpose_cvt<<<dim3(32, 32, 1), dim3(32, 8), 0, stream>>>(W_out, woutt, 1024, 1024);
  transpose_cvt<<<dim3(2, 2, 16), dim3(32, 8), 0, stream>>>(RF, rft, 64, 64);

  // qkv = xb @ wqkvt^T : M=16384 (64 tiles) x N=3072 (12 tiles), grid 768
  gemm256<0><<<768, 512, 0, stream>>>(xb, wqkvt, qkv, nullptr, 3072, 1024, 12, 96);
  phik_kv<<<dim3(8, 16, 4), 256, 0, stream>>>(qkv, rft, kvpart);
  kv_reduce<<<64, 256, 0, stream>>>(kvpart, kvt);
  phiq_out<<<dim3(32, 16, 4), 256, 0, stream>>>(qkv, rft, kvt, attno);
  // out = attno @ woutt^T + b : M=16384 x N=1024 (4 tiles), grid 256
  gemm256<1><<<256, 512, 0, stream>>>(attno, woutt, out, b_out, 1024, 1024, 4, 32);
}

// Round 6
// 230.207 us; speedup vs baseline: 1.0529x; 1.0529x over previous
//
#include <hip/hip_runtime.h>

// Performer (FAVOR+) attention, MI355X bf16-MFMA implementation.
// Round 6: R3 base + correctly-synchronized depth-4 staging.
// R5's NaN: vmcnt wait was AFTER the barrier (tile-top) -> wave read other
// waves' LDS slices before THEIR loads landed (vmcnt is per-wave). Fix: wait
// stays at q3 BEFORE its barrier (R3 structure), depth added by staging
// B(T+2) at q2 and A(T+2) at q3 (earliest WAR-legal), vmcnt(8).
// Youngest retired load is 4 phases old (R3: 1 phase). R4's packed epilogue
// (write-decoalescing) stays reverted.

typedef __attribute__((ext_vector_type(8))) short s8v;   // 8 x bf16 (4 VGPR)
typedef __attribute__((ext_vector_type(4))) short s4v;   // 4 x bf16
typedef __attribute__((ext_vector_type(4))) float f4v;   // MFMA acc
typedef __attribute__((ext_vector_type(4))) int   i4v;   // 16B chunk

#define MFMA16(a, b, c) __builtin_amdgcn_mfma_f32_16x16x32_bf16((a), (b), (c), 0, 0, 0)

__device__ __forceinline__ unsigned short f2bf(float f) {
  unsigned int u = __builtin_bit_cast(unsigned int, f);
  unsigned int r = (u + 0x7FFFu + ((u >> 16) & 1u)) >> 16;  // RNE
  return (unsigned short)r;
}

__device__ __forceinline__ int swz(int p) {          // involution, bits 7..9 -> 4..6
  return p ^ (((p >> 7) & 7) << 4);
}

__device__ __forceinline__ void gl_lds16(const void* g, void* l) {
  __builtin_amdgcn_global_load_lds(
      (const __attribute__((address_space(1))) void*)g,
      (__attribute__((address_space(3))) void*)l, 16, 0, 0);
}

// ---------------------------------------------------------------- prep
__global__ __launch_bounds__(256) void cvt_bf16(const float* __restrict__ in,
                                                unsigned short* __restrict__ out,
                                                int n4) {
  int i = blockIdx.x * 256 + threadIdx.x;
  if (i >= n4) return;
  f4v v = ((const f4v*)in)[i];
  s4v o;
#pragma unroll
  for (int j = 0; j < 4; ++j) o[j] = (short)f2bf(v[j]);
  ((s4v*)out)[i] = o;
}

// out[z][c][r] = bf16(in[z][r][c]); R,C multiples of 32. block (32,8)
__global__ __launch_bounds__(256) void transpose_cvt(const float* __restrict__ in,
                                                     unsigned short* __restrict__ out,
                                                     int R, int C) {
  __shared__ float tile[32][33];
  const int tx = threadIdx.x, ty = threadIdx.y;
  const int z = blockIdx.z;
  const float* inz = in + (size_t)z * R * C;
  unsigned short* outz = out + (size_t)z * R * C;
  const int c0 = blockIdx.x * 32, r0 = blockIdx.y * 32;
#pragma unroll
  for (int j = 0; j < 4; ++j)
    tile[ty + j * 8][tx] = inz[(size_t)(r0 + ty + j * 8) * C + c0 + tx];
  __syncthreads();
#pragma unroll
  for (int j = 0; j < 4; ++j)
    outz[(size_t)(c0 + ty + j * 8) * R + r0 + tx] = f2bf(tile[tx][ty + j * 8]);
}

// ---------------------------------------------------------------- GEMM 256x256
// C[M,N] = A[M,K] @ Bt[N,K]^T.  8-phase schedule, BK=64, 512 threads (8 waves,
// 2Mx4N), 128 KiB LDS = 2 dbuf x {A,B} x 2 halves x [128 rows][64 cols] bf16.
// LDS swizzle p ^= ((p>>7)&7)<<4 as inverse-swizzled global source + swizzled
// ds_read (rule 21). Phases: q0=(0,0), q1=(0,1), q2=(1,1), q3=(1,0).
// Region read phases (buffer d): A-parts read q0+q2 (mh0/mh1 rows), B-parts
// q0+q1 (nh0/nh1 rows). Staging (all for tile T+2, buffer T&1 — earliest
// WAR-legal): q2: B0,B1 (B last read q1, 1 barrier upstream); q3: A0,A1
// (A last read q2). Wait vmcnt(8) at q3 BEFORE its barrier: retires
// everything through A1(T+1) (issued 4 phases earlier); leaves the 8 loads
// of tile T+2 in flight. Cross-wave safe: wait -> s_barrier -> reads.
template <int MODE>
__global__ __launch_bounds__(512, 2) void gemm256(const unsigned short* __restrict__ A,
                                                  const unsigned short* __restrict__ Bt,
                                                  void* __restrict__ Cout,
                                                  const float* __restrict__ bias,
                                                  int Nn, int K, int NTN, int CPX) {
  __shared__ __align__(128) unsigned short smem[65536];  // 128 KiB
  const int t = threadIdx.x, w = t >> 6, lane = t & 63;
  const int wm = w >> 2, wn = w & 3;
  const int fr = lane & 15, c16 = (lane >> 4) * 16;
  const int nkt = K >> 6;

  // T1: XCD-bijective block swizzle (grid % 8 == 0)
  const int bid = blockIdx.x;
  const int wg = (bid & 7) * CPX + (bid >> 3);
  const int tm = wg / NTN, tn = wg % NTN;

  const unsigned short* gA = A + (size_t)tm * 256 * K;
  const unsigned short* gB = Bt + (size_t)tn * 256 * K;

  // per-thread pre-swizzled global source offsets for the 2 staging loads
  const int s0 = swz(t * 16);
  const int s1 = swz(8192 + t * 16);
  const int goff0 = (s0 >> 7) * K + ((s0 & 127) >> 1);
  const int goff1 = ((s1 - 8192) >> 7) * K + ((s1 & 127) >> 1) + 64 * K;
  const int woff = w * 1024;  // wave-uniform LDS byte offset

  // parts: 0=A rows 0-127, 1=A rows 128-255, 2=B rows 0-127, 3=B rows 128-255
  auto stage = [&](int T2, int part) {
    if (T2 >= nkt) return;
    char* reg = (char*)smem + (((T2 & 1) * 4 + part) << 14);
    const unsigned short* gp =
        (part < 2 ? gA : gB) + (size_t)((part & 1) * 128) * K + T2 * 64;
    gl_lds16(gp + goff0, reg + woff);
    gl_lds16(gp + goff1, reg + 8192 + woff);
  };

  f4v acc[8][4] = {};

  // prologue: tile0 (8 loads) + tile1 (8 loads); retire tile0, keep tile1 flying
  stage(0, 0); stage(0, 1); stage(0, 2); stage(0, 3);
  stage(1, 2); stage(1, 3); stage(1, 0); stage(1, 1);
  if (nkt > 1) { asm volatile("s_waitcnt vmcnt(8)" ::: "memory"); }
  else         { asm volatile("s_waitcnt vmcnt(0)" ::: "memory"); }
  __builtin_amdgcn_s_barrier();
  __builtin_amdgcn_sched_barrier(0);

  auto rdA = [&](int mh, s8v (&a)[4][2], const char* Ar) {
#pragma unroll
    for (int i = 0; i < 4; ++i)
#pragma unroll
      for (int ks = 0; ks < 2; ++ks) {
        int p = swz((mh * 64 + i * 16 + fr) * 128 + ks * 64 + c16);
        a[i][ks] = *(const s8v*)(Ar + p);
      }
  };
  auto rdB = [&](int nh, s8v (&b)[2][2], const char* Br, int brow) {
#pragma unroll
    for (int j = 0; j < 2; ++j)
#pragma unroll
      for (int ks = 0; ks < 2; ++ks) {
        int p = swz((brow + nh * 32 + j * 16 + fr) * 128 + ks * 64 + c16);
        b[j][ks] = *(const s8v*)(Br + p);
      }
  };
  auto mmac = [&](int mh, int nh, const s8v (&a)[4][2], const s8v (&b)[2][2]) {
    __builtin_amdgcn_s_setprio(1);
#pragma unroll
    for (int i = 0; i < 4; ++i)
#pragma unroll
      for (int j = 0; j < 2; ++j) {
        acc[mh * 4 + i][nh * 2 + j] = MFMA16(a[i][0], b[j][0], acc[mh * 4 + i][nh * 2 + j]);
        acc[mh * 4 + i][nh * 2 + j] = MFMA16(a[i][1], b[j][1], acc[mh * 4 + i][nh * 2 + j]);
      }
    __builtin_amdgcn_s_setprio(0);
  };

  const int brow = (wn & 1) * 64;
  for (int T = 0; T < nkt; ++T) {
    const int d = T & 1;
    const char* Ar = (const char*)smem + ((d * 4 + wm) << 14);
    const char* Br = (const char*)smem + ((d * 4 + 2 + (wn >> 1)) << 14);
    s8v a[4][2], b0[2][2], b1[2][2];
    // q0: quadrant (0,0) — no staging
    rdA(0, a, Ar); rdB(0, b0, Br, brow);
    __builtin_amdgcn_s_barrier();
    mmac(0, 0, a, b0);
    __builtin_amdgcn_s_barrier();
    __builtin_amdgcn_sched_barrier(0);
    // q1: quadrant (0,1) — reuse A; no staging
    rdB(1, b1, Br, brow);
    __builtin_amdgcn_s_barrier();
    mmac(0, 1, a, b1);
    __builtin_amdgcn_s_barrier();
    __builtin_amdgcn_sched_barrier(0);
    // q2: quadrant (1,1) — reuse B1; stage B(T+2) (B-parts free after q1)
    rdA(1, a, Ar); stage(T + 2, 2); stage(T + 2, 3);
    __builtin_amdgcn_s_barrier();
    mmac(1, 1, a, b1);
    __builtin_amdgcn_s_barrier();
    __builtin_amdgcn_sched_barrier(0);
    // q3: quadrant (1,0) — stage A(T+2) (A-parts free after q2); wait+barrier
    stage(T + 2, 0); stage(T + 2, 1);
    if (T < nkt - 2)       { asm volatile("s_waitcnt vmcnt(8)" ::: "memory"); }
    else                   { asm volatile("s_waitcnt vmcnt(0)" ::: "memory"); }
    __builtin_amdgcn_s_barrier();
    mmac(1, 0, a, b0);
    __builtin_amdgcn_s_barrier();
    __builtin_amdgcn_sched_barrier(0);
  }

  // epilogue (R3 layout: row <-> a, col <-> b)
#pragma unroll
  for (int m = 0; m < 8; ++m)
#pragma unroll
    for (int n = 0; n < 4; ++n) {
      const int row = tm * 256 + wm * 128 + m * 16 + (lane >> 4) * 4;
      const int col = tn * 256 + wn * 64 + n * 16 + fr;
      if (MODE == 0) {
        unsigned short* C = (unsigned short*)Cout;
#pragma unroll
        for (int r = 0; r < 4; ++r)
          C[(size_t)(row + r) * Nn + col] = f2bf(acc[m][n][r]);
      } else {
        float* C = (float*)Cout;
        const float bv = bias[col];
#pragma unroll
        for (int r = 0; r < 4; ++r)
          C[(size_t)(row + r) * Nn + col] = acc[m][n][r] + bv;
      }
    }
}

// ---------------------------------------------------------------- phi_k + kv
// block = (och, h, b); processes 512 tokens in 4 chunks of 128.
// kvpart[bh][och][80][64]: rows 0..63 = kv^T (d,r), row 64 = k_sum, 65..79 = 0.
__global__ __launch_bounds__(256) void phik_kv(const unsigned short* __restrict__ qkv,
                                               const unsigned short* __restrict__ RFt,
                                               float* __restrict__ kvpart) {
  __shared__ unsigned short RFl[2 * 64 * 32];   // [p][r][32]
  __shared__ unsigned short Kl[2 * 128 * 32];   // [p][n][32]
  __shared__ unsigned short pht[64 * 136];      // [r][n] (+pad)
  __shared__ unsigned short vt[80 * 136];       // [d][n] (+ones row 64)
  const int t = threadIdx.x, w = t >> 6, lane = t & 63;
  const int och = blockIdx.x, h = blockIdx.y, b = blockIdx.z;
  const int fr = lane & 15, kg = (lane >> 4) * 8;

#pragma unroll
  for (int i = 0; i < 2; ++i) {  // RF[h] -> RFl
    int unit = i * 256 + w * 64 + lane;
    int p = unit >> 8, rem = unit & 255;
    int r = rem >> 2, cg = (rem & 3) * 8;
    gl_lds16(RFt + ((h * 64 + r) * 64 + p * 32 + cg), &RFl[(i * 256 + w * 64) * 8]);
  }
  for (int i = t; i < 136; i += 256) vt[64 * 136 + i] = 0x3F80;     // ones row
  for (int i = t; i < 15 * 136; i += 256) vt[65 * 136 + i] = 0;     // zero pad rows

  f4v kvacc[5] = {};

  for (int c = 0; c < 4; ++c) {
    const int n0c = och * 512 + c * 128;
    const size_t rowbase = (size_t)(b * 4096 + n0c);
#pragma unroll
    for (int i = 0; i < 4; ++i) {  // K slice -> Kl
      int unit = i * 256 + w * 64 + lane;
      int p = unit >> 9, rem = unit & 511;
      int n = rem >> 2, cg = (rem & 3) * 8;
      gl_lds16(qkv + (rowbase + n) * 3072 + 1024 + h * 64 + p * 32 + cg,
               &Kl[(i * 256 + w * 64) * 8]);
    }
    i4v vreg[4];
#pragma unroll
    for (int it = 0; it < 4; ++it) {  // V slice -> regs
      int slot = it * 256 + t;
      vreg[it] = *(const i4v*)&qkv[(rowbase + (slot >> 3)) * 3072 + 2048 + h * 64 +
                                   (slot & 7) * 8];
    }
    __syncthreads();
    // phi_k = relu(K @ RF)
    f4v pacc[2][4] = {};
#pragma unroll
    for (int p = 0; p < 2; ++p) {
      s8v ka[2], rb[4];
#pragma unroll
      for (int m = 0; m < 2; ++m)
        ka[m] = *(const s8v*)&Kl[p * 4096 + (w * 32 + m * 16 + fr) * 32 + kg];
#pragma unroll
      for (int rf = 0; rf < 4; ++rf)
        rb[rf] = *(const s8v*)&RFl[p * 2048 + (rf * 16 + fr) * 32 + kg];
#pragma unroll
      for (int m = 0; m < 2; ++m)
#pragma unroll
        for (int rf = 0; rf < 4; ++rf)
          pacc[m][rf] = MFMA16(ka[m], rb[rf], pacc[m][rf]);
    }
    // v -> vt (transposed)
#pragma unroll
    for (int it = 0; it < 4; ++it) {
      int slot = it * 256 + t;
      int vn = slot >> 3, vdh = (slot & 7) * 8;
      const unsigned short* vr = (const unsigned short*)&vreg[it];
#pragma unroll
      for (int j = 0; j < 8; ++j) vt[(vdh + j) * 136 + vn] = vr[j];
    }
    // phi -> pht (transposed, relu, bf16)
#pragma unroll
    for (int m = 0; m < 2; ++m)
#pragma unroll
      for (int rf = 0; rf < 4; ++rf) {
        int r = rf * 16 + fr;
        int nb = w * 32 + m * 16 + (lane >> 4) * 4;
        s4v pk;
#pragma unroll
        for (int g = 0; g < 4; ++g) pk[g] = (short)f2bf(fmaxf(pacc[m][rf][g], 0.0f));
        *(s4v*)&pht[r * 136 + nb] = pk;
      }
    __syncthreads();
    // kv_aug[d][r] += vt @ pht^T  (wave w owns r-cols w*16..+15)
#pragma unroll
    for (int kst = 0; kst < 4; ++kst) {
      s8v pb = *(const s8v*)&pht[(w * 16 + fr) * 136 + kst * 32 + kg];
#pragma unroll
      for (int f = 0; f < 5; ++f) {
        s8v va = *(const s8v*)&vt[(f * 16 + fr) * 136 + kst * 32 + kg];
        kvacc[f] = MFMA16(va, pb, kvacc[f]);
      }
    }
  }
  const int bh = b * 16 + h;
  float* outp = kvpart + ((size_t)bh * 8 + och) * (80 * 64);
#pragma unroll
  for (int f = 0; f < 5; ++f) {
    int row = f * 16 + (lane >> 4) * 4;
    int col = w * 16 + fr;
#pragma unroll
    for (int g = 0; g < 4; ++g) outp[(row + g) * 64 + col] = kvacc[f][g];
  }
}

__global__ __launch_bounds__(256) void kv_reduce(const float* __restrict__ kvpart,
                                                 unsigned short* __restrict__ kvt) {
  const int bh = blockIdx.x, t = threadIdx.x;
  for (int i = t; i < 80 * 64; i += 256) {
    float s = 0.f;
#pragma unroll
    for (int c = 0; c < 8; ++c) s += kvpart[((size_t)bh * 8 + c) * 5120 + i];
    kvt[(size_t)bh * 5120 + i] = f2bf(s);
  }
}

// ---------------------------------------------------------------- phi_q + out
// block = (ch, h, b); 128 tokens. attno[token][h*64+d] = (phi_q@kv)/(phi_q.k_sum+eps)
__global__ __launch_bounds__(256) void phiq_out(const unsigned short* __restrict__ qkv,
                                                const unsigned short* __restrict__ RFt,
                                                const unsigned short* __restrict__ kvt,
                                                unsigned short* __restrict__ attno) {
  __shared__ unsigned short RFl[2 * 64 * 32];  // [p][r][32]
  __shared__ unsigned short Ql[2 * 128 * 32];  // [p][n][32]
  __shared__ unsigned short phl[128 * 72];     // [n][r] (+pad)
  __shared__ unsigned short kvl[80 * 72];      // [d][r] (+pad), row 64 = k_sum
  const int t = threadIdx.x, w = t >> 6, lane = t & 63;
  const int ch = blockIdx.x, h = blockIdx.y, b = blockIdx.z;
  const int fr = lane & 15, kg = (lane >> 4) * 8;
  const int bh = b * 16 + h;
  const size_t rowbase = (size_t)(b * 4096 + ch * 128);

#pragma unroll
  for (int i = 0; i < 2; ++i) {
    int unit = i * 256 + w * 64 + lane;
    int p = unit >> 8, rem = unit & 255;
    int r = rem >> 2, cg = (rem & 3) * 8;
    gl_lds16(RFt + ((h * 64 + r) * 64 + p * 32 + cg), &RFl[(i * 256 + w * 64) * 8]);
  }
#pragma unroll
  for (int i = 0; i < 4; ++i) {
    int unit = i * 256 + w * 64 + lane;
    int p = unit >> 9, rem = unit & 511;
    int n = rem >> 2, cg = (rem & 3) * 8;
    gl_lds16(qkv + (rowbase + n) * 3072 + h * 64 + p * 32 + cg,
             &Ql[(i * 256 + w * 64) * 8]);
  }
  for (int i = t; i < 640; i += 256) {  // kvt -> kvl (pad 64->72)
    int row = i >> 3, cg = (i & 7) * 8;
    *(i4v*)&kvl[row * 72 + cg] = *(const i4v*)&kvt[(size_t)bh * 5120 + row * 64 + cg];
  }
  __syncthreads();
  f4v pacc[2][4] = {};
#pragma unroll
  for (int p = 0; p < 2; ++p) {
    s8v qa[2], rb[4];
#pragma unroll
    for (int m = 0; m < 2; ++m)
      qa[m] = *(const s8v*)&Ql[p * 4096 + (w * 32 + m * 16 + fr) * 32 + kg];
#pragma unroll
    for (int rf = 0; rf < 4; ++rf)
      rb[rf] = *(const s8v*)&RFl[p * 2048 + (rf * 16 + fr) * 32 + kg];
#pragma unroll
    for (int m = 0; m < 2; ++m)
#pragma unroll
      for (int rf = 0; rf < 4; ++rf)
        pacc[m][rf] = MFMA16(qa[m], rb[rf], pacc[m][rf]);
  }
#pragma unroll
  for (int m = 0; m < 2; ++m)
#pragma unroll
    for (int rf = 0; rf < 4; ++rf) {
      int r = rf * 16 + fr;
      int nb = w * 32 + m * 16 + (lane >> 4) * 4;
#pragma unroll
      for (int g = 0; g < 4; ++g)
        phl[(nb + g) * 72 + r] = f2bf(fmaxf(pacc[m][rf][g], 0.0f));
    }
  __syncthreads();
  f4v acc[2][5] = {};
#pragma unroll
  for (int kst = 0; kst < 2; ++kst) {
    s8v pa[2], kb[5];
#pragma unroll
    for (int m = 0; m < 2; ++m)
      pa[m] = *(const s8v*)&phl[(w * 32 + m * 16 + fr) * 72 + kst * 32 + kg];
#pragma unroll
    for (int f = 0; f < 5; ++f)
      kb[f] = *(const s8v*)&kvl[(f * 16 + fr) * 72 + kst * 32 + kg];
#pragma unroll
    for (int m = 0; m < 2; ++m)
#pragma unroll
      for (int f = 0; f < 5; ++f) acc[m][f] = MFMA16(pa[m], kb[f], acc[m][f]);
  }
#pragma unroll
  for (int m = 0; m < 2; ++m)
#pragma unroll
    for (int g = 0; g < 4; ++g) {
      float nrm = __shfl(acc[m][4][g], lane & 48) + 1e-6f;  // col 64 = phi_q.k_sum
      int n = w * 32 + m * 16 + (lane >> 4) * 4 + g;
      size_t orow = rowbase + n;
#pragma unroll
      for (int f = 0; f < 4; ++f)
        attno[orow * 1024 + h * 64 + f * 16 + fr] = f2bf(acc[m][f][g] / nrm);
    }
}

// ---------------------------------------------------------------- launch
extern "C" void kernel_launch(void* const* d_in, const int* in_sizes, int n_in,
                              void* d_out, int out_size, void* d_ws, size_t ws_size,
                              hipStream_t stream) {
  const float* x = (const float*)d_in[0];      // [4,4096,1024]
  const float* W_qkv = (const float*)d_in[1];  // [1024,3072]
  const float* RF = (const float*)d_in[2];     // [16,64,64]
  const float* W_out = (const float*)d_in[3];  // [1024,1024]
  const float* b_out = (const float*)d_in[4];  // [1024]
  float* out = (float*)d_out;                  // [4,4096,1024]

  char* ws = (char*)d_ws;
  size_t off = 0;
  auto alloc = [&](size_t bytes) -> void* {
    void* p = ws + off;
    off += (bytes + 255) & ~(size_t)255;
    return p;
  };
  unsigned short* xb = (unsigned short*)alloc(16384ull * 1024 * 2);
  unsigned short* wqkvt = (unsigned short*)alloc(3072ull * 1024 * 2);
  unsigned short* woutt = (unsigned short*)alloc(1024ull * 1024 * 2);
  unsigned short* rft = (unsigned short*)alloc(16ull * 64 * 64 * 2);
  unsigned short* qkv = (unsigned short*)alloc(16384ull * 3072 * 2);
  float* kvpart = (float*)alloc(64ull * 8 * 80 * 64 * 4);
  unsigned short* kvt = (unsigned short*)alloc(64ull * 80 * 64 * 2);
  unsigned short* attno = (unsigned short*)alloc(16384ull * 1024 * 2);

  cvt_bf16<<<16384, 256, 0, stream>>>(x, xb, 4194304);
  transpose_cvt<<<dim3(96, 32, 1), dim3(32, 8), 0, stream>>>(W_qkv, wqkvt, 1024, 3072);
  transpose_cvt<<<dim3(32, 32, 1), dim3(32, 8), 0, stream>>>(W_out, woutt, 1024, 1024);
  transpose_cvt<<<dim3(2, 2, 16), dim3(32, 8), 0, stream>>>(RF, rft, 64, 64);

  // qkv = xb @ wqkvt^T : M=16384 (64 tiles) x N=3072 (12 tiles), grid 768
  gemm256<0><<<768, 512, 0, stream>>>(xb, wqkvt, qkv, nullptr, 3072, 1024, 12, 96);
  phik_kv<<<dim3(8, 16, 4), 256, 0, stream>>>(qkv, rft, kvpart);
  kv_reduce<<<64, 256, 0, stream>>>(kvpart, kvt);
  phiq_out<<<dim3(32, 16, 4), 256, 0, stream>>>(qkv, rft, kvt, attno);
  // out = attno @ woutt^T + b : M=16384 x N=1024 (4 tiles), grid 256
  gemm256<1><<<256, 512, 0, stream>>>(attno, woutt, out, b_out, 1024, 1024, 4, 32);
}

// Round 7
// 224.809 us; speedup vs baseline: 1.0782x; 1.0240x over previous
//
#include <hip/hip_runtime.h>

// Performer (FAVOR+) attention, MI355X bf16-MFMA implementation.
// Round 7: collapse GEMM K-loop to ONE barrier + one vmcnt(0) per K-tile.
// R3/R6's 8-barrier quadrant phases serialized LDS-read bursts against MFMA
// across all waves (q0: 96 wave-reads at once ~1150cy exposed; q3: LDS idle).
// New tile body: [vmcnt(0); s_barrier; sched_barrier; stage(T+1) x4;
// read A0,B0,B1; 32 MFMA; read A1; 32 MFMA] — waves free-run, LDS/MFMA/VMEM
// overlap wave-to-wave. WAR-safe with 1 barrier: every ds_read is consumed
// by an MFMA before the wave's next barrier arrival (in-order LDS completion
// + compiler lgkmcnt before use), so buffer d^1 reads are drained before any
// wave passes the barrier and restages it. vmcnt(0) BEFORE the barrier
// (per-wave counter; R5 lesson); free since loads are a full K-tile old.

typedef __attribute__((ext_vector_type(8))) short s8v;   // 8 x bf16 (4 VGPR)
typedef __attribute__((ext_vector_type(4))) short s4v;   // 4 x bf16
typedef __attribute__((ext_vector_type(4))) float f4v;   // MFMA acc
typedef __attribute__((ext_vector_type(4))) int   i4v;   // 16B chunk

#define MFMA16(a, b, c) __builtin_amdgcn_mfma_f32_16x16x32_bf16((a), (b), (c), 0, 0, 0)

__device__ __forceinline__ unsigned short f2bf(float f) {
  unsigned int u = __builtin_bit_cast(unsigned int, f);
  unsigned int r = (u + 0x7FFFu + ((u >> 16) & 1u)) >> 16;  // RNE
  return (unsigned short)r;
}

__device__ __forceinline__ int swz(int p) {          // involution, bits 7..9 -> 4..6
  return p ^ (((p >> 7) & 7) << 4);
}

__device__ __forceinline__ void gl_lds16(const void* g, void* l) {
  __builtin_amdgcn_global_load_lds(
      (const __attribute__((address_space(1))) void*)g,
      (__attribute__((address_space(3))) void*)l, 16, 0, 0);
}

// ---------------------------------------------------------------- prep
__global__ __launch_bounds__(256) void cvt_bf16(const float* __restrict__ in,
                                                unsigned short* __restrict__ out,
                                                int n4) {
  int i = blockIdx.x * 256 + threadIdx.x;
  if (i >= n4) return;
  f4v v = ((const f4v*)in)[i];
  s4v o;
#pragma unroll
  for (int j = 0; j < 4; ++j) o[j] = (short)f2bf(v[j]);
  ((s4v*)out)[i] = o;
}

// out[z][c][r] = bf16(in[z][r][c]); R,C multiples of 32. block (32,8)
__global__ __launch_bounds__(256) void transpose_cvt(const float* __restrict__ in,
                                                     unsigned short* __restrict__ out,
                                                     int R, int C) {
  __shared__ float tile[32][33];
  const int tx = threadIdx.x, ty = threadIdx.y;
  const int z = blockIdx.z;
  const float* inz = in + (size_t)z * R * C;
  unsigned short* outz = out + (size_t)z * R * C;
  const int c0 = blockIdx.x * 32, r0 = blockIdx.y * 32;
#pragma unroll
  for (int j = 0; j < 4; ++j)
    tile[ty + j * 8][tx] = inz[(size_t)(r0 + ty + j * 8) * C + c0 + tx];
  __syncthreads();
#pragma unroll
  for (int j = 0; j < 4; ++j)
    outz[(size_t)(c0 + ty + j * 8) * R + r0 + tx] = f2bf(tile[tx][ty + j * 8]);
}

// ---------------------------------------------------------------- GEMM 256x256
// C[M,N] = A[M,K] @ Bt[N,K]^T.  BK=64, 512 threads (8 waves, 2Mx4N),
// 128 KiB LDS = 2 dbuf x {A,B} x 2 halves x [128 rows][64 cols] bf16.
// LDS swizzle p ^= ((p>>7)&7)<<4 as inverse-swizzled global source + swizzled
// ds_read (rule 21). One barrier + one vmcnt(0) per K-tile (see header).
template <int MODE>
__global__ __launch_bounds__(512, 2) void gemm256(const unsigned short* __restrict__ A,
                                                  const unsigned short* __restrict__ Bt,
                                                  void* __restrict__ Cout,
                                                  const float* __restrict__ bias,
                                                  int Nn, int K, int NTN, int CPX) {
  __shared__ __align__(128) unsigned short smem[65536];  // 128 KiB
  const int t = threadIdx.x, w = t >> 6, lane = t & 63;
  const int wm = w >> 2, wn = w & 3;
  const int fr = lane & 15, c16 = (lane >> 4) * 16;
  const int nkt = K >> 6;

  // T1: XCD-bijective block swizzle (grid % 8 == 0)
  const int bid = blockIdx.x;
  const int wg = (bid & 7) * CPX + (bid >> 3);
  const int tm = wg / NTN, tn = wg % NTN;

  const unsigned short* gA = A + (size_t)tm * 256 * K;
  const unsigned short* gB = Bt + (size_t)tn * 256 * K;

  // per-thread pre-swizzled global source offsets for the 2 staging loads
  const int s0 = swz(t * 16);
  const int s1 = swz(8192 + t * 16);
  const int goff0 = (s0 >> 7) * K + ((s0 & 127) >> 1);
  const int goff1 = ((s1 - 8192) >> 7) * K + ((s1 & 127) >> 1) + 64 * K;
  const int woff = w * 1024;  // wave-uniform LDS byte offset

  // parts: 0=A rows 0-127, 1=A rows 128-255, 2=B rows 0-127, 3=B rows 128-255
  auto stage = [&](int T2, int part) {
    if (T2 >= nkt) return;
    char* reg = (char*)smem + (((T2 & 1) * 4 + part) << 14);
    const unsigned short* gp =
        (part < 2 ? gA : gB) + (size_t)((part & 1) * 128) * K + T2 * 64;
    gl_lds16(gp + goff0, reg + woff);
    gl_lds16(gp + goff1, reg + 8192 + woff);
  };

  f4v acc[8][4] = {};

  // prologue: tile0 (8 loads); waited at top of T=0 (one-time exposed latency)
  stage(0, 0); stage(0, 1); stage(0, 2); stage(0, 3);

  auto rdA = [&](int mh, s8v (&a)[4][2], const char* Ar) {
#pragma unroll
    for (int i = 0; i < 4; ++i)
#pragma unroll
      for (int ks = 0; ks < 2; ++ks) {
        int p = swz((mh * 64 + i * 16 + fr) * 128 + ks * 64 + c16);
        a[i][ks] = *(const s8v*)(Ar + p);
      }
  };
  auto rdB = [&](int nh, s8v (&b)[2][2], const char* Br, int brow) {
#pragma unroll
    for (int j = 0; j < 2; ++j)
#pragma unroll
      for (int ks = 0; ks < 2; ++ks) {
        int p = swz((brow + nh * 32 + j * 16 + fr) * 128 + ks * 64 + c16);
        b[j][ks] = *(const s8v*)(Br + p);
      }
  };
  auto mmac = [&](int mh, int nh, const s8v (&a)[4][2], const s8v (&b)[2][2]) {
    __builtin_amdgcn_s_setprio(1);
#pragma unroll
    for (int i = 0; i < 4; ++i)
#pragma unroll
      for (int j = 0; j < 2; ++j) {
        acc[mh * 4 + i][nh * 2 + j] = MFMA16(a[i][0], b[j][0], acc[mh * 4 + i][nh * 2 + j]);
        acc[mh * 4 + i][nh * 2 + j] = MFMA16(a[i][1], b[j][1], acc[mh * 4 + i][nh * 2 + j]);
      }
    __builtin_amdgcn_s_setprio(0);
  };

  const int brow = (wn & 1) * 64;
  for (int T = 0; T < nkt; ++T) {
    const int d = T & 1;
    const char* Ar = (const char*)smem + ((d * 4 + wm) << 14);
    const char* Br = (const char*)smem + ((d * 4 + 2 + (wn >> 1)) << 14);
    // tile-top: my loads for tile T landed -> barrier -> everyone's landed.
    asm volatile("s_waitcnt vmcnt(0)" ::: "memory");
    __builtin_amdgcn_s_barrier();
    __builtin_amdgcn_sched_barrier(0);
    // prefetch tile T+1 into buffer d^1 (WAR-safe: d^1's reads drained
    // before every wave's arrival at the barrier above)
    stage(T + 1, 0); stage(T + 1, 1); stage(T + 1, 2); stage(T + 1, 3);
    s8v a[4][2], b0[2][2], b1[2][2];
    rdA(0, a, Ar); rdB(0, b0, Br, brow); rdB(1, b1, Br, brow);
    mmac(0, 0, a, b0);
    mmac(0, 1, a, b1);
    rdA(1, a, Ar);
    mmac(1, 1, a, b1);
    mmac(1, 0, a, b0);
  }

  // epilogue (R3 layout: row <-> a, col <-> b)
#pragma unroll
  for (int m = 0; m < 8; ++m)
#pragma unroll
    for (int n = 0; n < 4; ++n) {
      const int row = tm * 256 + wm * 128 + m * 16 + (lane >> 4) * 4;
      const int col = tn * 256 + wn * 64 + n * 16 + fr;
      if (MODE == 0) {
        unsigned short* C = (unsigned short*)Cout;
#pragma unroll
        for (int r = 0; r < 4; ++r)
          C[(size_t)(row + r) * Nn + col] = f2bf(acc[m][n][r]);
      } else {
        float* C = (float*)Cout;
        const float bv = bias[col];
#pragma unroll
        for (int r = 0; r < 4; ++r)
          C[(size_t)(row + r) * Nn + col] = acc[m][n][r] + bv;
      }
    }
}

// ---------------------------------------------------------------- phi_k + kv
// block = (och, h, b); processes 512 tokens in 4 chunks of 128.
// kvpart[bh][och][80][64]: rows 0..63 = kv^T (d,r), row 64 = k_sum, 65..79 = 0.
__global__ __launch_bounds__(256) void phik_kv(const unsigned short* __restrict__ qkv,
                                               const unsigned short* __restrict__ RFt,
                                               float* __restrict__ kvpart) {
  __shared__ unsigned short RFl[2 * 64 * 32];   // [p][r][32]
  __shared__ unsigned short Kl[2 * 128 * 32];   // [p][n][32]
  __shared__ unsigned short pht[64 * 136];      // [r][n] (+pad)
  __shared__ unsigned short vt[80 * 136];       // [d][n] (+ones row 64)
  const int t = threadIdx.x, w = t >> 6, lane = t & 63;
  const int och = blockIdx.x, h = blockIdx.y, b = blockIdx.z;
  const int fr = lane & 15, kg = (lane >> 4) * 8;

#pragma unroll
  for (int i = 0; i < 2; ++i) {  // RF[h] -> RFl
    int unit = i * 256 + w * 64 + lane;
    int p = unit >> 8, rem = unit & 255;
    int r = rem >> 2, cg = (rem & 3) * 8;
    gl_lds16(RFt + ((h * 64 + r) * 64 + p * 32 + cg), &RFl[(i * 256 + w * 64) * 8]);
  }
  for (int i = t; i < 136; i += 256) vt[64 * 136 + i] = 0x3F80;     // ones row
  for (int i = t; i < 15 * 136; i += 256) vt[65 * 136 + i] = 0;     // zero pad rows

  f4v kvacc[5] = {};

  for (int c = 0; c < 4; ++c) {
    const int n0c = och * 512 + c * 128;
    const size_t rowbase = (size_t)(b * 4096 + n0c);
#pragma unroll
    for (int i = 0; i < 4; ++i) {  // K slice -> Kl
      int unit = i * 256 + w * 64 + lane;
      int p = unit >> 9, rem = unit & 511;
      int n = rem >> 2, cg = (rem & 3) * 8;
      gl_lds16(qkv + (rowbase + n) * 3072 + 1024 + h * 64 + p * 32 + cg,
               &Kl[(i * 256 + w * 64) * 8]);
    }
    i4v vreg[4];
#pragma unroll
    for (int it = 0; it < 4; ++it) {  // V slice -> regs
      int slot = it * 256 + t;
      vreg[it] = *(const i4v*)&qkv[(rowbase + (slot >> 3)) * 3072 + 2048 + h * 64 +
                                   (slot & 7) * 8];
    }
    __syncthreads();
    // phi_k = relu(K @ RF)
    f4v pacc[2][4] = {};
#pragma unroll
    for (int p = 0; p < 2; ++p) {
      s8v ka[2], rb[4];
#pragma unroll
      for (int m = 0; m < 2; ++m)
        ka[m] = *(const s8v*)&Kl[p * 4096 + (w * 32 + m * 16 + fr) * 32 + kg];
#pragma unroll
      for (int rf = 0; rf < 4; ++rf)
        rb[rf] = *(const s8v*)&RFl[p * 2048 + (rf * 16 + fr) * 32 + kg];
#pragma unroll
      for (int m = 0; m < 2; ++m)
#pragma unroll
        for (int rf = 0; rf < 4; ++rf)
          pacc[m][rf] = MFMA16(ka[m], rb[rf], pacc[m][rf]);
    }
    // v -> vt (transposed)
#pragma unroll
    for (int it = 0; it < 4; ++it) {
      int slot = it * 256 + t;
      int vn = slot >> 3, vdh = (slot & 7) * 8;
      const unsigned short* vr = (const unsigned short*)&vreg[it];
#pragma unroll
      for (int j = 0; j < 8; ++j) vt[(vdh + j) * 136 + vn] = vr[j];
    }
    // phi -> pht (transposed, relu, bf16)
#pragma unroll
    for (int m = 0; m < 2; ++m)
#pragma unroll
      for (int rf = 0; rf < 4; ++rf) {
        int r = rf * 16 + fr;
        int nb = w * 32 + m * 16 + (lane >> 4) * 4;
        s4v pk;
#pragma unroll
        for (int g = 0; g < 4; ++g) pk[g] = (short)f2bf(fmaxf(pacc[m][rf][g], 0.0f));
        *(s4v*)&pht[r * 136 + nb] = pk;
      }
    __syncthreads();
    // kv_aug[d][r] += vt @ pht^T  (wave w owns r-cols w*16..+15)
#pragma unroll
    for (int kst = 0; kst < 4; ++kst) {
      s8v pb = *(const s8v*)&pht[(w * 16 + fr) * 136 + kst * 32 + kg];
#pragma unroll
      for (int f = 0; f < 5; ++f) {
        s8v va = *(const s8v*)&vt[(f * 16 + fr) * 136 + kst * 32 + kg];
        kvacc[f] = MFMA16(va, pb, kvacc[f]);
      }
    }
  }
  const int bh = b * 16 + h;
  float* outp = kvpart + ((size_t)bh * 8 + och) * (80 * 64);
#pragma unroll
  for (int f = 0; f < 5; ++f) {
    int row = f * 16 + (lane >> 4) * 4;
    int col = w * 16 + fr;
#pragma unroll
    for (int g = 0; g < 4; ++g) outp[(row + g) * 64 + col] = kvacc[f][g];
  }
}

__global__ __launch_bounds__(256) void kv_reduce(const float* __restrict__ kvpart,
                                                 unsigned short* __restrict__ kvt) {
  const int bh = blockIdx.x, t = threadIdx.x;
  for (int i = t; i < 80 * 64; i += 256) {
    float s = 0.f;
#pragma unroll
    for (int c = 0; c < 8; ++c) s += kvpart[((size_t)bh * 8 + c) * 5120 + i];
    kvt[(size_t)bh * 5120 + i] = f2bf(s);
  }
}

// ---------------------------------------------------------------- phi_q + out
// block = (ch, h, b); 128 tokens. attno[token][h*64+d] = (phi_q@kv)/(phi_q.k_sum+eps)
__global__ __launch_bounds__(256) void phiq_out(const unsigned short* __restrict__ qkv,
                                                const unsigned short* __restrict__ RFt,
                                                const unsigned short* __restrict__ kvt,
                                                unsigned short* __restrict__ attno) {
  __shared__ unsigned short RFl[2 * 64 * 32];  // [p][r][32]
  __shared__ unsigned short Ql[2 * 128 * 32];  // [p][n][32]
  __shared__ unsigned short phl[128 * 72];     // [n][r] (+pad)
  __shared__ unsigned short kvl[80 * 72];      // [d][r] (+pad), row 64 = k_sum
  const int t = threadIdx.x, w = t >> 6, lane = t & 63;
  const int ch = blockIdx.x, h = blockIdx.y, b = blockIdx.z;
  const int fr = lane & 15, kg = (lane >> 4) * 8;
  const int bh = b * 16 + h;
  const size_t rowbase = (size_t)(b * 4096 + ch * 128);

#pragma unroll
  for (int i = 0; i < 2; ++i) {
    int unit = i * 256 + w * 64 + lane;
    int p = unit >> 8, rem = unit & 255;
    int r = rem >> 2, cg = (rem & 3) * 8;
    gl_lds16(RFt + ((h * 64 + r) * 64 + p * 32 + cg), &RFl[(i * 256 + w * 64) * 8]);
  }
#pragma unroll
  for (int i = 0; i < 4; ++i) {
    int unit = i * 256 + w * 64 + lane;
    int p = unit >> 9, rem = unit & 511;
    int n = rem >> 2, cg = (rem & 3) * 8;
    gl_lds16(qkv + (rowbase + n) * 3072 + h * 64 + p * 32 + cg,
             &Ql[(i * 256 + w * 64) * 8]);
  }
  for (int i = t; i < 640; i += 256) {  // kvt -> kvl (pad 64->72)
    int row = i >> 3, cg = (i & 7) * 8;
    *(i4v*)&kvl[row * 72 + cg] = *(const i4v*)&kvt[(size_t)bh * 5120 + row * 64 + cg];
  }
  __syncthreads();
  f4v pacc[2][4] = {};
#pragma unroll
  for (int p = 0; p < 2; ++p) {
    s8v qa[2], rb[4];
#pragma unroll
    for (int m = 0; m < 2; ++m)
      qa[m] = *(const s8v*)&Ql[p * 4096 + (w * 32 + m * 16 + fr) * 32 + kg];
#pragma unroll
    for (int rf = 0; rf < 4; ++rf)
      rb[rf] = *(const s8v*)&RFl[p * 2048 + (rf * 16 + fr) * 32 + kg];
#pragma unroll
    for (int m = 0; m < 2; ++m)
#pragma unroll
      for (int rf = 0; rf < 4; ++rf)
        pacc[m][rf] = MFMA16(qa[m], rb[rf], pacc[m][rf]);
  }
#pragma unroll
  for (int m = 0; m < 2; ++m)
#pragma unroll
    for (int rf = 0; rf < 4; ++rf) {
      int r = rf * 16 + fr;
      int nb = w * 32 + m * 16 + (lane >> 4) * 4;
#pragma unroll
      for (int g = 0; g < 4; ++g)
        phl[(nb + g) * 72 + r] = f2bf(fmaxf(pacc[m][rf][g], 0.0f));
    }
  __syncthreads();
  f4v acc[2][5] = {};
#pragma unroll
  for (int kst = 0; kst < 2; ++kst) {
    s8v pa[2], kb[5];
#pragma unroll
    for (int m = 0; m < 2; ++m)
      pa[m] = *(const s8v*)&phl[(w * 32 + m * 16 + fr) * 72 + kst * 32 + kg];
#pragma unroll
    for (int f = 0; f < 5; ++f)
      kb[f] = *(const s8v*)&kvl[(f * 16 + fr) * 72 + kst * 32 + kg];
#pragma unroll
    for (int m = 0; m < 2; ++m)
#pragma unroll
      for (int f = 0; f < 5; ++f) acc[m][f] = MFMA16(pa[m], kb[f], acc[m][f]);
  }
#pragma unroll
  for (int m = 0; m < 2; ++m)
#pragma unroll
    for (int g = 0; g < 4; ++g) {
      float nrm = __shfl(acc[m][4][g], lane & 48) + 1e-6f;  // col 64 = phi_q.k_sum
      int n = w * 32 + m * 16 + (lane >> 4) * 4 + g;
      size_t orow = rowbase + n;
#pragma unroll
      for (int f = 0; f < 4; ++f)
        attno[orow * 1024 + h * 64 + f * 16 + fr] = f2bf(acc[m][f][g] / nrm);
    }
}

// ---------------------------------------------------------------- launch
extern "C" void kernel_launch(void* const* d_in, const int* in_sizes, int n_in,
                              void* d_out, int out_size, void* d_ws, size_t ws_size,
                              hipStream_t stream) {
  const float* x = (const float*)d_in[0];      // [4,4096,1024]
  const float* W_qkv = (const float*)d_in[1];  // [1024,3072]
  const float* RF = (const float*)d_in[2];     // [16,64,64]
  const float* W_out = (const float*)d_in[3];  // [1024,1024]
  const float* b_out = (const float*)d_in[4];  // [1024]
  float* out = (float*)d_out;                  // [4,4096,1024]

  char* ws = (char*)d_ws;
  size_t off = 0;
  auto alloc = [&](size_t bytes) -> void* {
    void* p = ws + off;
    off += (bytes + 255) & ~(size_t)255;
    return p;
  };
  unsigned short* xb = (unsigned short*)alloc(16384ull * 1024 * 2);
  unsigned short* wqkvt = (unsigned short*)alloc(3072ull * 1024 * 2);
  unsigned short* woutt = (unsigned short*)alloc(1024ull * 1024 * 2);
  unsigned short* rft = (unsigned short*)alloc(16ull * 64 * 64 * 2);
  unsigned short* qkv = (unsigned short*)alloc(16384ull * 3072 * 2);
  float* kvpart = (float*)alloc(64ull * 8 * 80 * 64 * 4);
  unsigned short* kvt = (unsigned short*)alloc(64ull * 80 * 64 * 2);
  unsigned short* attno = (unsigned short*)alloc(16384ull * 1024 * 2);

  cvt_bf16<<<16384, 256, 0, stream>>>(x, xb, 4194304);
  transpose_cvt<<<dim3(96, 32, 1), dim3(32, 8), 0, stream>>>(W_qkv, wqkvt, 1024, 3072);
  transpose_cvt<<<dim3(32, 32, 1), dim3(32, 8), 0, stream>>>(W_out, woutt, 1024, 1024);
  transpose_cvt<<<dim3(2, 2, 16), dim3(32, 8), 0, stream>>>(RF, rft, 64, 64);

  // qkv = xb @ wqkvt^T : M=16384 (64 tiles) x N=3072 (12 tiles), grid 768
  gemm256<0><<<768, 512, 0, stream>>>(xb, wqkvt, qkv, nullptr, 3072, 1024, 12, 96);
  phik_kv<<<dim3(8, 16, 4), 256, 0, stream>>>(qkv, rft, kvpart);
  kv_reduce<<<64, 256, 0, stream>>>(kvpart, kvt);
  phiq_out<<<dim3(32, 16, 4), 256, 0, stream>>>(qkv, rft, kvt, attno);
  // out = attno @ woutt^T + b : M=16384 x N=1024 (4 tiles), grid 256
  gemm256<1><<<256, 512, 0, stream>>>(attno, woutt, out, b_out, 1024, 1024, 4, 32);
}